// Round 1
// baseline (211.211 us; speedup 1.0000x reference)
//
#include <hip/hip_runtime.h>

// OpeningLoss2D: grey opening with flat 2x2 SE (scipy grey_opening size=2
// semantics, 'reflect' boundary == edge clamp for pad 1), then
// mean((x - opening(x))^2) over [8,16,512,512] fp32.  Output: 1 fp32 scalar.
//
// smooth[i][j] = max_{(a,b) in {i,i2}x{j,j2}} er(a,b),  i2=min(i+1,H-1)
// er(a,b)      = min over x rows {max(a-1,0),a}, cols {max(b-1,0),b}
//
// Hardcoded layout: H=W=512 (shifts/masks), planes = N>>18.

#define BLK 256
#define GRID 2048

__global__ __launch_bounds__(BLK) void opening_partial_kernel(
    const float* __restrict__ x, float* __restrict__ partial, int nGroups)
{
    float acc = 0.f;
    const int stride = gridDim.x * blockDim.x;
    for (int g = blockIdx.x * blockDim.x + threadIdx.x; g < nGroups; g += stride) {
        const int j = (g & 127) << 2;          // starting col of this 4-pixel group
        const int i = (g >> 7) & 511;          // row
        const long long planeOff = ((long long)(g >> 16)) << 18;
        const float* r1 = x + planeOff + ((long long)i << 9);
        const float* r0 = (i > 0)   ? r1 - 512 : r1;   // clamped row i-1
        const float* r2 = (i < 511) ? r1 + 512 : r1;   // clamped row i+1

        const float4 v0 = *(const float4*)(r0 + j);
        const float4 v1 = *(const float4*)(r1 + j);
        const float4 v2 = *(const float4*)(r2 + j);
        const int jm = (j > 0)   ? j - 1 : 0;
        const int jp = (j < 508) ? j + 4 : 511;
        const float a0 = r0[jm], e0 = r0[jp];
        const float a1 = r1[jm], e1 = r1[jp];
        const float a2 = r2[jm], e2 = r2[jp];

        // per-row horizontal pair-mins: m[c] = min over cols {c-1,c} (clamped)
        // for window positions j .. j+4
        float m0[5] = { fminf(a0, v0.x), fminf(v0.x, v0.y), fminf(v0.y, v0.z),
                        fminf(v0.z, v0.w), fminf(v0.w, e0) };
        float m1[5] = { fminf(a1, v1.x), fminf(v1.x, v1.y), fminf(v1.y, v1.z),
                        fminf(v1.z, v1.w), fminf(v1.w, e1) };
        float m2[5] = { fminf(a2, v2.x), fminf(v2.x, v2.y), fminf(v2.y, v2.z),
                        fminf(v2.z, v2.w), fminf(v2.w, e2) };

        // vertical mins: erA = er(i, col), erB = er(i2, col)
        // er(i2,.) rows = {max(i2-1,0), i2}: i<511 -> {i, i+1}; i=511 -> {i-1, i}
        float erA[5], erB[5];
        const bool notBottom = (i < 511);
        #pragma unroll
        for (int c = 0; c < 5; ++c) {
            erA[c] = fminf(m0[c], m1[c]);
            const float inner = notBottom ? m1[c] : m0[c];
            erB[c] = fminf(inner, m2[c]);
        }

        const bool lastChunk = (j == 508);     // pixel k=3 sits at col W-1
        const float xv[4] = { v1.x, v1.y, v1.z, v1.w };
        #pragma unroll
        for (int k = 0; k < 4; ++k) {
            float eA2 = erA[k + 1], eB2 = erB[k + 1];
            if (lastChunk && k == 3) { eA2 = erA[3]; eB2 = erB[3]; }  // j2 window folds back
            const float dl = fmaxf(fmaxf(erA[k], eA2), fmaxf(erB[k], eB2));
            const float d = xv[k] - dl;
            acc = fmaf(d, d, acc);
        }
    }

    // wave (64) shuffle reduce, then LDS across 4 waves, one partial per block
    #pragma unroll
    for (int off = 32; off > 0; off >>= 1)
        acc += __shfl_down(acc, off, 64);
    __shared__ float s[BLK / 64];
    if ((threadIdx.x & 63) == 0) s[threadIdx.x >> 6] = acc;
    __syncthreads();
    if (threadIdx.x == 0) {
        float t = 0.f;
        #pragma unroll
        for (int w = 0; w < BLK / 64; ++w) t += s[w];
        partial[blockIdx.x] = t;
    }
}

__global__ __launch_bounds__(256) void final_reduce_kernel(
    const float* __restrict__ partial, float* __restrict__ out, int n, float invN)
{
    float acc = 0.f;
    for (int idx = threadIdx.x; idx < n; idx += blockDim.x) acc += partial[idx];
    #pragma unroll
    for (int off = 32; off > 0; off >>= 1)
        acc += __shfl_down(acc, off, 64);
    __shared__ float s[4];
    if ((threadIdx.x & 63) == 0) s[threadIdx.x >> 6] = acc;
    __syncthreads();
    if (threadIdx.x == 0)
        out[0] = (s[0] + s[1] + s[2] + s[3]) * invN;
}

extern "C" void kernel_launch(void* const* d_in, const int* in_sizes, int n_in,
                              void* d_out, int out_size, void* d_ws, size_t ws_size,
                              hipStream_t stream) {
    const float* x = (const float*)d_in[0];
    float* out = (float*)d_out;
    float* ws = (float*)d_ws;          // GRID floats of scratch (8 KB)
    const int N = in_sizes[0];         // 8*16*512*512 = 33554432
    const int nGroups = N >> 2;

    opening_partial_kernel<<<GRID, BLK, 0, stream>>>(x, ws, nGroups);
    final_reduce_kernel<<<1, 256, 0, stream>>>(ws, out, GRID, 1.0f / (float)N);
}

// Round 2
// 188.393 us; speedup vs baseline: 1.1211x; 1.1211x over previous
//
#include <hip/hip_runtime.h>

// OpeningLoss2D: grey opening, flat 2x2 SE (scipy size=2, 'reflect' == edge
// clamp for pad 1), then mean((x - opening(x))^2) over [8,16,512,512] fp32.
//
//   h[a][j]  = min(x[a][j-1], x[a][j])           (col clamp at 0)
//   er[a]    = min(h[a-1], h[a])                 (row clamp at 0)
//   g[a][j]  = max(er[a][j], er[a][j+1])         (col clamp at 511)
//   smooth[i]= max(g[i], g[i+1])                 (row clamp at 511)
//
// Row-streaming strips: one wave = full 512-col row (8 cols/lane), sweeps
// R=16 output rows keeping h/g/x of the previous row in registers. Each
// input row loaded once per strip (18/16 = 1.125x fetch). Horizontal
// neighbors via __shfl (no extra VMEM).

#define BLK 256
#define R_STRIP 16
#define GRID 1024   // 4096 strips / 4 waves-per-block

__device__ __forceinline__ void compute_h(float4 u0, float4 u1, int lane,
                                          float h[9]) {
    float xl = __shfl_up(u1.w, 1, 64);    // lane-1's col c0-1
    float xr = __shfl_down(u0.x, 1, 64);  // lane+1's col c0+8
    if (lane == 0)  xl = u0.x;            // col 0: h = x[0]
    if (lane == 63) xr = u1.w;            // col 512 -> clamp (value unused at 511)
    h[0] = fminf(xl, u0.x);
    h[1] = fminf(u0.x, u0.y);
    h[2] = fminf(u0.y, u0.z);
    h[3] = fminf(u0.z, u0.w);
    h[4] = fminf(u0.w, u1.x);
    h[5] = fminf(u1.x, u1.y);
    h[6] = fminf(u1.y, u1.z);
    h[7] = fminf(u1.z, u1.w);
    h[8] = fminf(u1.w, xr);
}

__global__ __launch_bounds__(BLK) void opening_strip_kernel(
    const float* __restrict__ x, float* __restrict__ partial, int nStrips)
{
    const int lane = threadIdx.x & 63;
    const int waveId = blockIdx.x * (BLK / 64) + (threadIdx.x >> 6);
    const int totalWaves = gridDim.x * (BLK / 64);
    float acc = 0.f;

    for (int strip = waveId; strip < nStrips; strip += totalWaves) {
        const int plane = strip >> 5;               // 512/R_STRIP = 32 strips/plane
        const int rs = (strip & 31) * R_STRIP;
        const int re = rs + R_STRIP - 1;            // <= 511
        const int aEnd = (re < 511) ? re + 1 : 511;
        const float* pl = x + (((long long)plane) << 18) + (lane << 3);

        float hp[9], gp[8], xk[8];

        // prologue: h for row max(rs-1, 0)
        {
            const int a0 = (rs > 0) ? rs - 1 : 0;
            const float* rp = pl + ((long long)a0 << 9);
            float4 u0 = *(const float4*)(rp);
            float4 u1 = *(const float4*)(rp + 4);
            compute_h(u0, u1, lane, hp);
        }
        // preload row rs
        float4 n0, n1;
        {
            const float* rp = pl + ((long long)rs << 9);
            n0 = *(const float4*)(rp);
            n1 = *(const float4*)(rp + 4);
        }

        for (int a = rs; a <= aEnd; ++a) {
            const float4 u0 = n0, u1 = n1;
            if (a < aEnd) {                          // prefetch next row
                const float* np = pl + ((long long)(a + 1) << 9);
                n0 = *(const float4*)(np);
                n1 = *(const float4*)(np + 4);
            }
            float hc[9], er[9], gc[8];
            compute_h(u0, u1, lane, hc);
            #pragma unroll
            for (int c = 0; c < 9; ++c) er[c] = fminf(hp[c], hc[c]);
            if (lane == 63) er[8] = er[7];           // col-511 clamp for g
            #pragma unroll
            for (int c = 0; c < 8; ++c) gc[c] = fmaxf(er[c], er[c + 1]);

            if (a > rs) {                            // emit output row a-1
                #pragma unroll
                for (int k = 0; k < 8; ++k) {
                    const float d = xk[k] - fmaxf(gp[k], gc[k]);
                    acc = fmaf(d, d, acc);
                }
            }
            #pragma unroll
            for (int c = 0; c < 9; ++c) hp[c] = hc[c];
            #pragma unroll
            for (int c = 0; c < 8; ++c) gp[c] = gc[c];
            xk[0] = u0.x; xk[1] = u0.y; xk[2] = u0.z; xk[3] = u0.w;
            xk[4] = u1.x; xk[5] = u1.y; xk[6] = u1.z; xk[7] = u1.w;
        }
        if (re == 511) {                             // row 511: smooth = g[511]
            #pragma unroll
            for (int k = 0; k < 8; ++k) {
                const float d = xk[k] - gp[k];
                acc = fmaf(d, d, acc);
            }
        }
    }

    // wave shuffle reduce, then LDS across 4 waves, one partial per block
    #pragma unroll
    for (int off = 32; off > 0; off >>= 1)
        acc += __shfl_down(acc, off, 64);
    __shared__ float s[BLK / 64];
    if ((threadIdx.x & 63) == 0) s[threadIdx.x >> 6] = acc;
    __syncthreads();
    if (threadIdx.x == 0) {
        float t = 0.f;
        #pragma unroll
        for (int w = 0; w < BLK / 64; ++w) t += s[w];
        partial[blockIdx.x] = t;
    }
}

__global__ __launch_bounds__(256) void final_reduce_kernel(
    const float* __restrict__ partial, float* __restrict__ out, int n, float invN)
{
    float acc = 0.f;
    for (int idx = threadIdx.x; idx < n; idx += blockDim.x) acc += partial[idx];
    #pragma unroll
    for (int off = 32; off > 0; off >>= 1)
        acc += __shfl_down(acc, off, 64);
    __shared__ float s[4];
    if ((threadIdx.x & 63) == 0) s[threadIdx.x >> 6] = acc;
    __syncthreads();
    if (threadIdx.x == 0)
        out[0] = (s[0] + s[1] + s[2] + s[3]) * invN;
}

extern "C" void kernel_launch(void* const* d_in, const int* in_sizes, int n_in,
                              void* d_out, int out_size, void* d_ws, size_t ws_size,
                              hipStream_t stream) {
    const float* x = (const float*)d_in[0];
    float* out = (float*)d_out;
    float* ws = (float*)d_ws;                  // GRID floats of scratch
    const int N = in_sizes[0];                 // 8*16*512*512
    const int nStrips = (N >> 18) << 5;        // planes * 32

    opening_strip_kernel<<<GRID, BLK, 0, stream>>>(x, ws, nStrips);
    final_reduce_kernel<<<1, 256, 0, stream>>>(ws, out, GRID, 1.0f / (float)N);
}